// Round 1
// baseline (664.500 us; speedup 1.0000x reference)
//
#include <hip/hip_runtime.h>
#include <hip/hip_cooperative_groups.h>
#include <math.h>

#define DD 5          // embedding dim
#define NFREQ 50      // frequencies per coordinate
// ENC_DIM = 4*NFREQ = 200; W row per gene = 200*5 = 1000 floats

namespace cg = cooperative_groups;

struct Params {
  const float2* coords;
  const int* gm;
  const int* n2; int g2;
  const int* n3; int g3;
  const int* n4; int g4;
  const int* lci;
  const int* genes_oi;
  const float* W;
  const float* wexpr;
  const float* bias;
  int F; int n_genes; int total4;
  float* out;
  float* emb;
  int* order;
  int* starts;
  int* cnt;
  int* cur;
  unsigned char* mask;
};

// ---------------------------------------------------------------- attention + inline pool
// Attention output never round-trips through emb: each group thread pools its
// fragments' projections directly (saves 3.6MB write + 3.6MB re-read + a pass).
template <int SZ>
__device__ __forceinline__ void attn_group_pool(const int* __restrict__ idx,
                                                const float* __restrict__ emb,
                                                const int* __restrict__ lci,
                                                const int* __restrict__ genes_oi,
                                                const float* __restrict__ wexpr,
                                                int n_genes, float* __restrict__ out) {
  int fid[SZ];
  float x[SZ][DD];
#pragma unroll
  for (int a = 0; a < SZ; ++a) {
    fid[a] = idx[a];
    const float* p = emb + (size_t)fid[a] * DD;
#pragma unroll
    for (int d = 0; d < DD; ++d) x[a][d] = p[d];
  }
  const float scale = rsqrtf((float)SZ);   // reference scales by sqrt(seq_len)
#pragma unroll
  for (int a = 0; a < SZ; ++a) {
    float sc[SZ];
    float m = -1e30f;
#pragma unroll
    for (int b = 0; b < SZ; ++b) {
      float dt = 0.f;
#pragma unroll
      for (int d = 0; d < DD; ++d) dt += x[a][d] * x[b][d];
      sc[b] = dt * scale;
      m = fmaxf(m, sc[b]);
    }
    float sum = 0.f;
#pragma unroll
    for (int b = 0; b < SZ; ++b) {
      sc[b] = __expf(sc[b] - m);
      sum += sc[b];
    }
    float inv = 1.f / sum;
    // project attention output row a straight into the pooled cell x gene sum
    int ix = lci[fid[a]];
    int g = genes_oi[ix % n_genes];
    const float* w = wexpr + (size_t)g * DD;
    float s = 0.f;
#pragma unroll
    for (int d = 0; d < DD; ++d) {
      float acc = 0.f;
#pragma unroll
      for (int b = 0; b < SZ; ++b) acc += sc[b] * x[b][d];
      s += acc * inv * w[d];
    }
    atomicAdd(out + ix, s);
  }
}

// ---------------------------------------------------------------- fused pipeline
// One cooperative launch; phases separated by grid.sync():
//   P0: zero cnt/mask, out <- bias (20MB, dependency-free, overlaps zeroing)
//   P1: gene histogram (global atomics) + group-membership mask set
//   P2: block 0 scans cnt -> starts[] and seeds global cursors cur[]
//   P3: scatter: order[atomicAdd(cur[g])] = i   (order within gene is free)
//   P4: embed: one block per gene, wave-uniform W -> scalar loads
//   P5: attention groups w/ inline pool; ungrouped fragments pooled via mask
__global__ __launch_bounds__(256, 4) void fused_kernel(Params P) {
  cg::grid_group grid = cg::this_grid();
  const int tid = threadIdx.x;
  const int gtid = blockIdx.x * blockDim.x + tid;
  const int gs = gridDim.x * blockDim.x;
  const int F = P.F;
  const int n_genes = P.n_genes;

  __shared__ float s_freq[NFREQ];
  __shared__ int s_ws[4];
  if (tid < NFREQ)
    s_freq[tid] = exp2f(-0.39863137f * (float)(tid + 1));  // 1000^(-2i/50)

  // ---- P0: zero cnt + mask; out <- bias broadcast (independent of everything)
  for (int j = gtid; j < n_genes; j += gs) P.cnt[j] = 0;
  int F4 = F >> 2;
  int* mask4 = (int*)P.mask;
  for (int i = gtid; i < F4; i += gs) mask4[i] = 0;
  for (int i = (F4 << 2) + gtid; i < F; i += gs) P.mask[i] = 0;
  for (int v4 = gtid; v4 < P.total4; v4 += gs) {
    int idx = v4 * 4;
    int j = idx % n_genes;          // n_genes % 4 == 0 -> same row
    float4 vv;
    vv.x = P.bias[P.genes_oi[j + 0]];
    vv.y = P.bias[P.genes_oi[j + 1]];
    vv.z = P.bias[P.genes_oi[j + 2]];
    vv.w = P.bias[P.genes_oi[j + 3]];
    reinterpret_cast<float4*>(P.out)[v4] = vv;
  }
  grid.sync();

  // ---- P1: histogram + group mask
  for (int i = gtid; i < F; i += gs) atomicAdd(&P.cnt[P.gm[i]], 1);
  for (int i = gtid; i < P.g2 * 2; i += gs) P.mask[P.n2[i]] = 1;
  for (int i = gtid; i < P.g3 * 3; i += gs) P.mask[P.n3[i]] = 1;
  for (int i = gtid; i < P.g4 * 4; i += gs) P.mask[P.n4[i]] = 1;
  grid.sync();

  // ---- P2: block 0 scans cnt -> starts, cur  (n_genes <= 1024)
  if (blockIdx.x == 0) {
    int lane = tid & 63, wv = tid >> 6;
    int4 v = make_int4(0, 0, 0, 0);
    if (4 * tid < n_genes) v = ((const int4*)P.cnt)[tid];
    int p = v.x + v.y + v.z + v.w;
    int ip = p;
#pragma unroll
    for (int off = 1; off < 64; off <<= 1) {
      int q = __shfl_up(ip, off);
      if (lane >= off) ip += q;
    }
    if (lane == 63) s_ws[wv] = ip;
    __syncthreads();
    int add = 0;
#pragma unroll
    for (int i = 0; i < 4; ++i)
      if (i < wv) add += s_ws[i];
    int excl = add + ip - p;
    int4 e;
    e.x = excl;
    e.y = excl + v.x;
    e.z = e.y + v.y;
    e.w = e.z + v.z;
    if (4 * tid < n_genes) {
      ((int4*)P.starts)[tid] = e;
      ((int4*)P.cur)[tid] = e;
      if (4 * tid + 4 == n_genes) P.starts[n_genes] = e.w + v.w;  // == F
    }
  }
  grid.sync();

  // ---- P3: scatter by gene via global cursors (order within gene irrelevant)
  for (int i = gtid; i < F; i += gs) {
    int g = P.gm[i];
    int p = atomicAdd(&P.cur[g], 1);
    P.order[p] = i;
  }
  grid.sync();

  // ---- P4: embed — one block per gene: W addresses wave-uniform -> s_loads
  for (int g = blockIdx.x; g < n_genes; g += gridDim.x) {
    int s0 = P.starts[g];
    int s1 = P.starts[g + 1];
    const float* __restrict__ Wg = P.W + (size_t)g * (4 * NFREQ * DD);
    for (int i = s0 + tid; i < s1; i += blockDim.x) {
      int f = P.order[i];
      float2 xy = P.coords[f];
      float a0 = 0.f, a1 = 0.f, a2 = 0.f, a3 = 0.f, a4 = 0.f;
      for (int k = 0; k < NFREQ; ++k) {
        float fr = s_freq[k];
        float ax = xy.x * fr;
        float ay = xy.y * fr;
        float sx = __sinf(ax), cx = __cosf(ax);
        float sy = __sinf(ay), cy = __cosf(ay);
        const float* w0s = Wg + (2 * k) * DD;               // coord0 sin row
        const float* w0c = w0s + DD;                        // coord0 cos row
        const float* w1s = Wg + (2 * NFREQ + 2 * k) * DD;   // coord1 sin row
        const float* w1c = w1s + DD;                        // coord1 cos row
        a0 += sx * w0s[0] + cx * w0c[0] + sy * w1s[0] + cy * w1c[0];
        a1 += sx * w0s[1] + cx * w0c[1] + sy * w1s[1] + cy * w1c[1];
        a2 += sx * w0s[2] + cx * w0c[2] + sy * w1s[2] + cy * w1c[2];
        a3 += sx * w0s[3] + cx * w0c[3] + sy * w1s[3] + cy * w1c[3];
        a4 += sx * w0s[4] + cx * w0c[4] + sy * w1s[4] + cy * w1c[4];
      }
      float* e = P.emb + (size_t)f * DD;
      e[0] = 1.f / (1.f + __expf(-a0));
      e[1] = 1.f / (1.f + __expf(-a1));
      e[2] = 1.f / (1.f + __expf(-a2));
      e[3] = 1.f / (1.f + __expf(-a3));
      e[4] = 1.f / (1.f + __expf(-a4));
    }
  }
  grid.sync();

  // ---- P5: attention groups (pool fused in); then pool ungrouped via mask
  int gtot = P.g2 + P.g3 + P.g4;
  for (int w = gtid; w < gtot; w += gs) {
    if (w < P.g2)
      attn_group_pool<2>(P.n2 + (size_t)w * 2, P.emb, P.lci, P.genes_oi,
                         P.wexpr, n_genes, P.out);
    else if (w < P.g2 + P.g3)
      attn_group_pool<3>(P.n3 + (size_t)(w - P.g2) * 3, P.emb, P.lci,
                         P.genes_oi, P.wexpr, n_genes, P.out);
    else
      attn_group_pool<4>(P.n4 + (size_t)(w - P.g2 - P.g3) * 4, P.emb, P.lci,
                         P.genes_oi, P.wexpr, n_genes, P.out);
  }
  for (int f = gtid; f < F; f += gs) {
    if (P.mask[f]) continue;
    int ix = P.lci[f];
    int g = P.genes_oi[ix % n_genes];
    const float* e = P.emb + (size_t)f * DD;
    const float* w = P.wexpr + (size_t)g * DD;
    float s = e[0] * w[0] + e[1] * w[1] + e[2] * w[2] + e[3] * w[3] + e[4] * w[4];
    atomicAdd(P.out + ix, s);
  }
}

// ---------------------------------------------------------------- launch
extern "C" void kernel_launch(void* const* d_in, const int* in_sizes, int n_in,
                              void* d_out, int out_size, void* d_ws, size_t ws_size,
                              hipStream_t stream) {
  Params P;
  P.coords   = (const float2*)d_in[0];
  P.gm       = (const int*)d_in[1];
  P.n2       = (const int*)d_in[2];
  P.n3       = (const int*)d_in[3];
  P.n4       = (const int*)d_in[4];
  P.lci      = (const int*)d_in[5];
  P.genes_oi = (const int*)d_in[6];
  P.W        = (const float*)d_in[7];
  P.wexpr    = (const float*)d_in[8];
  P.bias     = (const float*)d_in[9];
  P.out      = (float*)d_out;

  P.F       = in_sizes[1];
  P.n_genes = in_sizes[6];
  P.g2 = in_sizes[2] / 2;
  P.g3 = in_sizes[3] / 3;
  P.g4 = in_sizes[4] / 4;
  P.total4 = out_size / 4;

  char* ws = (char*)d_ws;
  size_t off = 0;
  P.emb    = (float*)(ws + off); off += (size_t)P.F * DD * sizeof(float);
  off = (off + 15) & ~(size_t)15;
  P.order  = (int*)(ws + off);   off += (size_t)P.F * sizeof(int);
  off = (off + 15) & ~(size_t)15;
  P.starts = (int*)(ws + off);   off += (size_t)(P.n_genes + 4) * sizeof(int);
  off = (off + 15) & ~(size_t)15;
  P.cnt    = (int*)(ws + off);   off += (size_t)P.n_genes * sizeof(int);
  off = (off + 15) & ~(size_t)15;
  P.cur    = (int*)(ws + off);   off += (size_t)P.n_genes * sizeof(int);
  off = (off + 15) & ~(size_t)15;
  P.mask   = (unsigned char*)(ws + off); off += (size_t)P.F;

  // Co-residency-safe grid, computed once. __launch_bounds__(256,4) caps VGPR
  // at 128 (4 waves/SIMD) and LDS is ~220B, so expect 4 blocks/CU * 256 CU = 1024.
  static int GRID = 0;
  if (GRID == 0) {
    int nb = 0;
    if (hipOccupancyMaxActiveBlocksPerMultiprocessor(&nb, fused_kernel, 256, 0)
            != hipSuccess || nb < 1)
      nb = 1;
    int ncu = 0;
    if (hipDeviceGetAttribute(&ncu, hipDeviceAttributeMultiprocessorCount, 0)
            != hipSuccess || ncu < 1)
      ncu = 256;
    int cap = nb * ncu;
    GRID = cap < 1024 ? cap : 1024;
  }

  void* args[] = { (void*)&P };
  hipLaunchCooperativeKernel((void*)fused_kernel, dim3(GRID), dim3(256),
                             args, 0, stream);
}

// Round 2
// 142.917 us; speedup vs baseline: 4.6495x; 4.6495x over previous
//
#include <hip/hip_runtime.h>
#include <math.h>

#define DD 5          // embedding dim
#define NFREQ 50      // frequencies per coordinate
#define NB 128        // sort blocks
// ENC_DIM = 4*NFREQ = 200; W row per gene = 200*5 = 1000 floats

// ---------------------------------------------------------------- K1: hist + mask-zero + out-init
// Blocks < NB histogram their contiguous chunk into LDS, write per-block counts
// transposed bc[bin*NB + b]. ALL blocks grid-stride: zero the group mask and
// broadcast bias into out (20MB) — fills the device while the histogram runs.
// Kernel boundary orders everything for K2/K5.
__global__ __launch_bounds__(256) void hist_init_kernel(
    const int* __restrict__ gm, int F, int chunk,
    int* __restrict__ bc, int n_genes, int* __restrict__ done,
    unsigned char* __restrict__ mask,
    float* __restrict__ out, const float* __restrict__ bias,
    const int* __restrict__ genes_oi, int total4) {
  __shared__ int cnt[1000];
  const int gtid = blockIdx.x * blockDim.x + threadIdx.x;
  const int gs = gridDim.x * blockDim.x;
  if (gtid == 0) *done = 0;
  // zero group-membership mask (bytes, int4-wide where possible)
  int F4 = F >> 2;
  int* mask4 = (int*)mask;
  for (int i = gtid; i < F4; i += gs) mask4[i] = 0;
  for (int i = (F4 << 2) + gtid; i < F; i += gs) mask[i] = 0;
  // out <- bias broadcast (row-repeating; n_genes % 4 == 0 -> same row per float4)
  for (int v4 = gtid; v4 < total4; v4 += gs) {
    int idx = v4 * 4;
    int j = idx % n_genes;
    float4 vv;
    vv.x = bias[genes_oi[j + 0]];
    vv.y = bias[genes_oi[j + 1]];
    vv.z = bias[genes_oi[j + 2]];
    vv.w = bias[genes_oi[j + 3]];
    reinterpret_cast<float4*>(out)[v4] = vv;
  }
  // block-local histogram
  if (blockIdx.x < NB) {
    for (int j = threadIdx.x; j < n_genes; j += blockDim.x) cnt[j] = 0;
    __syncthreads();
    int b = blockIdx.x;
    int lo = b * chunk;
    int hi = min(F, lo + chunk);
    for (int i = lo + threadIdx.x; i < hi; i += blockDim.x)
      atomicAdd(&cnt[gm[i]], 1);
    __syncthreads();
    for (int j = threadIdx.x; j < n_genes; j += blockDim.x)
      bc[j * NB + b] = cnt[j];
  }
}

// ---------------------------------------------------------------- K2: per-bin scan + starts + mask-set
// One wave per bin (4 bins/block): exclusive-scan the bin's NB=128 block
// counts in-register (int2 + shfl), emit bin total. The LAST block to finish
// (device-atomic ticket) scans the 1000 bin totals -> starts[]. All blocks
// additionally set the group mask (ordered after K1's zero by kernel boundary).
__global__ __launch_bounds__(256) void binscan_starts_kernel(
    int* __restrict__ bc, int n_genes, int* __restrict__ totals,
    int* __restrict__ starts, int* __restrict__ done, int nblocks,
    unsigned char* __restrict__ mask,
    const int* __restrict__ n2, int c2,
    const int* __restrict__ n3, int c3,
    const int* __restrict__ n4, int c4) {
  __shared__ int s_amlast;
  __shared__ int s_ws[4];
  const int gtid = blockIdx.x * blockDim.x + threadIdx.x;
  const int gs = gridDim.x * blockDim.x;
  int lane = threadIdx.x & 63;
  int wv = threadIdx.x >> 6;               // 0..3
  int bin = blockIdx.x * 4 + wv;
  if (bin < n_genes) {
    int2* row = (int2*)(bc + (size_t)bin * NB);   // 64 int2 per row
    int2 v = row[lane];
    int p = v.x + v.y;
    int ip = p;
#pragma unroll
    for (int off = 1; off < 64; off <<= 1) {
      int q = __shfl_up(ip, off);
      if (lane >= off) ip += q;
    }
    int base = ip - p;                      // exclusive prefix of this lane's pair
    int2 e;
    e.x = base;
    e.y = base + v.x;
    row[lane] = e;
    if (lane == 63) totals[bin] = ip;
  }
  // group-membership mask set (independent of the scan)
  for (int i = gtid; i < c2; i += gs) mask[n2[i]] = 1;
  for (int i = gtid; i < c3; i += gs) mask[n3[i]] = 1;
  for (int i = gtid; i < c4; i += gs) mask[n4[i]] = 1;
  __syncthreads();
  if (threadIdx.x == 0) {
    __threadfence();                        // publish totals
    int tk = atomicAdd(done, 1);
    s_amlast = (tk == nblocks - 1);
  }
  __syncthreads();
  if (!s_amlast) return;
  __threadfence();                          // acquire all totals
  // ---- scan 1000 totals with this block (n_genes % 4 == 0)
  int t = threadIdx.x;
  int4 v = make_int4(0, 0, 0, 0);
  if (4 * t < n_genes) v = ((const int4*)totals)[t];
  int p = v.x + v.y + v.z + v.w;
  int ip = p;
#pragma unroll
  for (int off = 1; off < 64; off <<= 1) {
    int q = __shfl_up(ip, off);
    if (lane >= off) ip += q;
  }
  if (lane == 63) s_ws[wv] = ip;
  __syncthreads();
  int add = 0;
#pragma unroll
  for (int i = 0; i < 4; ++i)
    if (i < wv) add += s_ws[i];
  int excl = add + ip - p;
  int4 e;
  e.x = excl;
  e.y = excl + v.x;
  e.z = e.y + v.y;
  e.w = e.z + v.z;
  if (4 * t < n_genes) ((int4*)starts)[t] = e;
  if (4 * t + 4 == n_genes) starts[n_genes] = e.w + v.w;   // grand total
}

// ---------------------------------------------------------------- K3: scatter by gene
// LDS cursors seeded with this block's global offset per bin; LDS atomics only.
__global__ __launch_bounds__(256) void blockscatter_kernel(
    const int* __restrict__ gm, int F, int chunk,
    const int* __restrict__ bc, const int* __restrict__ starts,
    int* __restrict__ order, int n_genes) {
  __shared__ int cur[1000];
  int b = blockIdx.x;
  for (int j = threadIdx.x; j < n_genes; j += blockDim.x)
    cur[j] = starts[j] + bc[j * NB + b];
  __syncthreads();
  int lo = b * chunk;
  int hi = min(F, lo + chunk);
  for (int i = lo + threadIdx.x; i < hi; i += blockDim.x) {
    int g = gm[i];
    int p = atomicAdd(&cur[g], 1);
    order[p] = i;
  }
}

// ---------------------------------------------------------------- K4: fragment embedding
// One block per gene: W addresses are wave-uniform -> scalar (SMEM) loads.
// Frequency table hoisted to LDS (saves 50 exp2f per fragment).
__global__ __launch_bounds__(256) void embed_kernel(
    const float2* __restrict__ coords, const int* __restrict__ order,
    const int* __restrict__ starts, const float* __restrict__ W,
    float* __restrict__ emb) {
  __shared__ float s_freq[NFREQ];
  if (threadIdx.x < NFREQ)
    s_freq[threadIdx.x] = exp2f(-0.39863137f * (float)(threadIdx.x + 1));
  __syncthreads();
  int g = blockIdx.x;
  int s0 = starts[g];
  int s1 = starts[g + 1];
  const float* __restrict__ Wg = W + (size_t)g * (4 * NFREQ * DD);

  for (int i = s0 + threadIdx.x; i < s1; i += blockDim.x) {
    int f = order[i];
    float2 xy = coords[f];
    float a0 = 0.f, a1 = 0.f, a2 = 0.f, a3 = 0.f, a4 = 0.f;
    for (int k = 0; k < NFREQ; ++k) {
      float fr = s_freq[k];
      float ax = xy.x * fr;
      float ay = xy.y * fr;
      float sx = __sinf(ax), cx = __cosf(ax);
      float sy = __sinf(ay), cy = __cosf(ay);
      const float* w0s = Wg + (2 * k) * DD;               // coord0 sin row
      const float* w0c = w0s + DD;                        // coord0 cos row
      const float* w1s = Wg + (2 * NFREQ + 2 * k) * DD;   // coord1 sin row
      const float* w1c = w1s + DD;                        // coord1 cos row
      a0 += sx * w0s[0] + cx * w0c[0] + sy * w1s[0] + cy * w1c[0];
      a1 += sx * w0s[1] + cx * w0c[1] + sy * w1s[1] + cy * w1c[1];
      a2 += sx * w0s[2] + cx * w0c[2] + sy * w1s[2] + cy * w1c[2];
      a3 += sx * w0s[3] + cx * w0c[3] + sy * w1s[3] + cy * w1c[3];
      a4 += sx * w0s[4] + cx * w0c[4] + sy * w1s[4] + cy * w1c[4];
    }
    float* e = emb + (size_t)f * DD;
    e[0] = 1.f / (1.f + __expf(-a0));
    e[1] = 1.f / (1.f + __expf(-a1));
    e[2] = 1.f / (1.f + __expf(-a2));
    e[3] = 1.f / (1.f + __expf(-a3));
    e[4] = 1.f / (1.f + __expf(-a4));
  }
}

// ---------------------------------------------------------------- attention group + inline pool
// The attention output never round-trips through emb: each group thread pools
// its fragments' projections straight into out (saves emb writeback + re-read).
template <int SZ>
__device__ __forceinline__ void attn_group_pool(const int* __restrict__ idx,
                                                const float* __restrict__ emb,
                                                const int* __restrict__ lci,
                                                const int* __restrict__ genes_oi,
                                                const float* __restrict__ wexpr,
                                                int n_genes, float* __restrict__ out) {
  int fid[SZ];
  float x[SZ][DD];
#pragma unroll
  for (int a = 0; a < SZ; ++a) {
    fid[a] = idx[a];
    const float* p = emb + (size_t)fid[a] * DD;
#pragma unroll
    for (int d = 0; d < DD; ++d) x[a][d] = p[d];
  }
  const float scale = rsqrtf((float)SZ);   // reference scales by sqrt(seq_len)
#pragma unroll
  for (int a = 0; a < SZ; ++a) {
    float sc[SZ];
    float m = -1e30f;
#pragma unroll
    for (int b = 0; b < SZ; ++b) {
      float dt = 0.f;
#pragma unroll
      for (int d = 0; d < DD; ++d) dt += x[a][d] * x[b][d];
      sc[b] = dt * scale;
      m = fmaxf(m, sc[b]);
    }
    float sum = 0.f;
#pragma unroll
    for (int b = 0; b < SZ; ++b) {
      sc[b] = __expf(sc[b] - m);
      sum += sc[b];
    }
    float inv = 1.f / sum;
    int ix = lci[fid[a]];
    int g = genes_oi[ix % n_genes];
    const float* w = wexpr + (size_t)g * DD;
    float s = 0.f;
#pragma unroll
    for (int d = 0; d < DD; ++d) {
      float acc = 0.f;
#pragma unroll
      for (int b = 0; b < SZ; ++b) acc += sc[b] * x[b][d];
      s += acc * w[d];
    }
    atomicAdd(out + ix, s * inv);
  }
}

// ---------------------------------------------------------------- K5: attention+pool
// Groups pool inline; ungrouped fragments (mask==0) pool raw emb.
// out already holds bias (K1); mask built in K1/K2.
__global__ __launch_bounds__(256) void attn_pool_kernel(
    const int* __restrict__ n2, int g2,
    const int* __restrict__ n3, int g3,
    const int* __restrict__ n4, int g4,
    const float* __restrict__ emb, const int* __restrict__ lci,
    const int* __restrict__ genes_oi, const float* __restrict__ wexpr,
    const unsigned char* __restrict__ mask,
    int F, int n_genes, float* __restrict__ out) {
  int gtid = blockIdx.x * blockDim.x + threadIdx.x;
  int gs = gridDim.x * blockDim.x;
  int gtot = g2 + g3 + g4;
  for (int w = gtid; w < gtot; w += gs) {
    if (w < g2)
      attn_group_pool<2>(n2 + (size_t)w * 2, emb, lci, genes_oi, wexpr, n_genes, out);
    else if (w < g2 + g3)
      attn_group_pool<3>(n3 + (size_t)(w - g2) * 3, emb, lci, genes_oi, wexpr, n_genes, out);
    else
      attn_group_pool<4>(n4 + (size_t)(w - g2 - g3) * 4, emb, lci, genes_oi, wexpr, n_genes, out);
  }
  for (int f = gtid; f < F; f += gs) {
    if (mask[f]) continue;
    int ix = lci[f];
    int g = genes_oi[ix % n_genes];
    const float* e = emb + (size_t)f * DD;
    const float* w = wexpr + (size_t)g * DD;
    float s = e[0] * w[0] + e[1] * w[1] + e[2] * w[2] + e[3] * w[3] + e[4] * w[4];
    atomicAdd(out + ix, s);
  }
}

// ---------------------------------------------------------------- launch
extern "C" void kernel_launch(void* const* d_in, const int* in_sizes, int n_in,
                              void* d_out, int out_size, void* d_ws, size_t ws_size,
                              hipStream_t stream) {
  const float2* coords  = (const float2*)d_in[0];
  const int* gm         = (const int*)d_in[1];
  const int* n2         = (const int*)d_in[2];
  const int* n3         = (const int*)d_in[3];
  const int* n4         = (const int*)d_in[4];
  const int* lci        = (const int*)d_in[5];
  const int* genes_oi   = (const int*)d_in[6];
  const float* W        = (const float*)d_in[7];
  const float* wexpr    = (const float*)d_in[8];
  const float* bias     = (const float*)d_in[9];
  float* out            = (float*)d_out;

  const int F       = in_sizes[1];
  const int n_genes = in_sizes[6];
  const int c2 = in_sizes[2];
  const int c3 = in_sizes[3];
  const int c4 = in_sizes[4];
  const int g2 = c2 / 2;
  const int g3 = c3 / 3;
  const int g4 = c4 / 4;

  char* ws = (char*)d_ws;
  size_t off = 0;
  float* emb   = (float*)(ws + off); off += (size_t)F * DD * sizeof(float);
  int* order   = (int*)(ws + off);   off += (size_t)F * sizeof(int);
  int* bc      = (int*)(ws + off);   off += (size_t)n_genes * NB * sizeof(int);
  off = (off + 15) & ~(size_t)15;
  int* starts  = (int*)(ws + off);   off += (size_t)(n_genes + 4) * sizeof(int);
  off = (off + 15) & ~(size_t)15;
  int* totals  = (int*)(ws + off);   off += (size_t)n_genes * sizeof(int);
  int* done    = (int*)(ws + off);   off += 4 * sizeof(int);
  off = (off + 15) & ~(size_t)15;
  unsigned char* mask = (unsigned char*)(ws + off); off += (size_t)F;

  const int tb = 256;
  const int chunk = (F + NB - 1) / NB;
  const int total4 = out_size / 4;

  hist_init_kernel<<<1024, tb, 0, stream>>>(gm, F, chunk, bc, n_genes, done,
                                            mask, out, bias, genes_oi, total4);
  int scan_blocks = (n_genes + 3) / 4;    // one wave per bin, 4 bins/block
  binscan_starts_kernel<<<scan_blocks, tb, 0, stream>>>(bc, n_genes, totals,
                                                        starts, done, scan_blocks,
                                                        mask, n2, c2, n3, c3, n4, c4);
  blockscatter_kernel<<<NB, tb, 0, stream>>>(gm, F, chunk, bc, starts, order, n_genes);
  embed_kernel<<<n_genes, tb, 0, stream>>>(coords, order, starts, W, emb);
  attn_pool_kernel<<<1250, tb, 0, stream>>>(n2, g2, n3, g3, n4, g4,
                                            emb, lci, genes_oi, wexpr,
                                            mask, F, n_genes, out);
}